// Round 1
// baseline (2694.934 us; speedup 1.0000x reference)
//
#include <hip/hip_runtime.h>
#include <math.h>

#define N_NODES 100000
#define E_EDGES 1600000
#define HALF_E  (E_EDGES / 2)

__device__ __forceinline__ float bcast(float v, int k) { return __shfl(v, k, 64); }

// ---------------- h = x @ w_in + b_in   (N x 128 -> N x 64) ----------------
__global__ __launch_bounds__(256) void k_lin_in(const float* __restrict__ x,
                                                const float* __restrict__ w,
                                                const float* __restrict__ b,
                                                float* __restrict__ h) {
    __shared__ float ws[128 * 64];
    __shared__ float bs[64];
    for (int i = threadIdx.x; i < 128 * 64; i += 256) ws[i] = w[i];
    if (threadIdx.x < 64) bs[threadIdx.x] = b[threadIdx.x];
    __syncthreads();
    const int lane = threadIdx.x & 63;
    const int wid  = threadIdx.x >> 6;
    const int wavesTotal = gridDim.x * 4;
    for (int r = blockIdx.x * 4 + wid; r < N_NODES; r += wavesTotal) {
        float xlo = x[r * 128 + lane];
        float xhi = x[r * 128 + 64 + lane];
        float acc = bs[lane];
#pragma unroll
        for (int k = 0; k < 64; ++k) acc = fmaf(bcast(xlo, k), ws[k * 64 + lane], acc);
#pragma unroll
        for (int k = 0; k < 64; ++k) acc = fmaf(bcast(xhi, k), ws[(64 + k) * 64 + lane], acc);
        h[r * 64 + lane] = acc;
    }
}

// ---------------- msg = relu(relu(h@m1+b1)@m2+b2)  per NODE ----------------
__global__ __launch_bounds__(256) void k_msg(const float* __restrict__ h,
                                             const float* __restrict__ w1,
                                             const float* __restrict__ b1,
                                             const float* __restrict__ w2,
                                             const float* __restrict__ b2,
                                             float* __restrict__ msg) {
    __shared__ float w1s[64 * 64], w2s[64 * 64];
    __shared__ float b1s[64], b2s[64];
    for (int i = threadIdx.x; i < 64 * 64; i += 256) { w1s[i] = w1[i]; w2s[i] = w2[i]; }
    if (threadIdx.x < 64) { b1s[threadIdx.x] = b1[threadIdx.x]; b2s[threadIdx.x] = b2[threadIdx.x]; }
    __syncthreads();
    const int lane = threadIdx.x & 63;
    const int wid  = threadIdx.x >> 6;
    const int wavesTotal = gridDim.x * 4;
    for (int r = blockIdx.x * 4 + wid; r < N_NODES; r += wavesTotal) {
        float hv = h[r * 64 + lane];
        float a1 = b1s[lane];
#pragma unroll
        for (int k = 0; k < 64; ++k) a1 = fmaf(bcast(hv, k), w1s[k * 64 + lane], a1);
        float t = fmaxf(a1, 0.0f);
        float a2 = b2s[lane];
#pragma unroll
        for (int k = 0; k < 64; ++k) a2 = fmaf(bcast(t, k), w2s[k * 64 + lane], a2);
        msg[r * 64 + lane] = fmaxf(a2, 0.0f);
    }
}

// ---------------- deg[row[e]] += 1 ----------------
__global__ __launch_bounds__(256) void k_deg(const int* __restrict__ rowIdx,
                                             float* __restrict__ deg) {
    for (int e = blockIdx.x * 256 + threadIdx.x; e < E_EDGES; e += gridDim.x * 256)
        atomicAdd(&deg[rowIdx[e]], 1.0f);
}

// ---------------- agg[row[e]] += msg[col[e]]  (wave per edge) ----------------
__global__ __launch_bounds__(256) void k_scatter(const int* __restrict__ rowIdx,
                                                 const int* __restrict__ colIdx,
                                                 const float* __restrict__ msg,
                                                 float* __restrict__ agg) {
    const int lane = threadIdx.x & 63;
    const int wid  = threadIdx.x >> 6;
    const int wavesTotal = gridDim.x * 4;
    for (int e = blockIdx.x * 4 + wid; e < E_EDGES; e += wavesTotal) {
        int r = rowIdx[e];
        int c = colIdx[e];
        float v = msg[c * 64 + lane];
        atomicAdd(&agg[r * 64 + lane], v);
    }
}

// ------- h += relu(concat(h, agg/clip(deg,1)) @ u1 + b1) @ u2 + b2  (in place) -------
__global__ __launch_bounds__(256) void k_update(float* __restrict__ h,
                                                const float* __restrict__ agg,
                                                const float* __restrict__ deg,
                                                const float* __restrict__ u1,
                                                const float* __restrict__ b1,
                                                const float* __restrict__ u2,
                                                const float* __restrict__ b2) {
    __shared__ float u1s[128 * 64], u2s[64 * 64];
    __shared__ float b1s[64], b2s[64];
    for (int i = threadIdx.x; i < 128 * 64; i += 256) u1s[i] = u1[i];
    for (int i = threadIdx.x; i < 64 * 64; i += 256) u2s[i] = u2[i];
    if (threadIdx.x < 64) { b1s[threadIdx.x] = b1[threadIdx.x]; b2s[threadIdx.x] = b2[threadIdx.x]; }
    __syncthreads();
    const int lane = threadIdx.x & 63;
    const int wid  = threadIdx.x >> 6;
    const int wavesTotal = gridDim.x * 4;
    for (int r = blockIdx.x * 4 + wid; r < N_NODES; r += wavesTotal) {
        float hv = h[r * 64 + lane];
        float dv = deg[r];
        float av = agg[r * 64 + lane] / fmaxf(dv, 1.0f);
        float a1 = b1s[lane];
#pragma unroll
        for (int k = 0; k < 64; ++k) a1 = fmaf(bcast(hv, k), u1s[k * 64 + lane], a1);
#pragma unroll
        for (int k = 0; k < 64; ++k) a1 = fmaf(bcast(av, k), u1s[(64 + k) * 64 + lane], a1);
        float t = fmaxf(a1, 0.0f);
        float a2 = b2s[lane];
#pragma unroll
        for (int k = 0; k < 64; ++k) a2 = fmaf(bcast(t, k), u2s[k * 64 + lane], a2);
        h[r * 64 + lane] = hv + a2;
    }
}

// ------- hA[v] = h[v]@h1w[0:64]   + deg[v]*h1w[128] + h1b
//         hB[v] = h[v]@h1w[64:128] + deg[v]*h1w[129] -------
__global__ __launch_bounds__(256) void k_headpre(const float* __restrict__ h,
                                                 const float* __restrict__ deg,
                                                 const float* __restrict__ w,
                                                 const float* __restrict__ b,
                                                 float* __restrict__ hA,
                                                 float* __restrict__ hB) {
    __shared__ float wsA[64 * 64], wsB[64 * 64];
    __shared__ float wdeg[2 * 64];
    __shared__ float bs[64];
    for (int i = threadIdx.x; i < 64 * 64; i += 256) { wsA[i] = w[i]; wsB[i] = w[64 * 64 + i]; }
    if (threadIdx.x < 128) wdeg[threadIdx.x] = w[128 * 64 + threadIdx.x];
    if (threadIdx.x < 64) bs[threadIdx.x] = b[threadIdx.x];
    __syncthreads();
    const int lane = threadIdx.x & 63;
    const int wid  = threadIdx.x >> 6;
    const int wavesTotal = gridDim.x * 4;
    for (int r = blockIdx.x * 4 + wid; r < N_NODES; r += wavesTotal) {
        float hv = h[r * 64 + lane];
        float dv = deg[r];
        float aA = bs[lane] + dv * wdeg[lane];
        float aB = dv * wdeg[64 + lane];
#pragma unroll
        for (int k = 0; k < 64; ++k) {
            float hk = bcast(hv, k);
            aA = fmaf(hk, wsA[k * 64 + lane], aA);
            aB = fmaf(hk, wsB[k * 64 + lane], aB);
        }
        hA[r * 64 + lane] = aA;
        hB[r * 64 + lane] = aB;
    }
}

// ------- out[e] = out[e+HALF] = softplus(relu(hA[src]+hB[dst]) . h2w + h2b) + 1e-6 -------
__global__ __launch_bounds__(256) void k_head(const int* __restrict__ rowIdx,
                                              const int* __restrict__ colIdx,
                                              const float* __restrict__ hA,
                                              const float* __restrict__ hB,
                                              const float* __restrict__ w2,
                                              const float* __restrict__ b2,
                                              float* __restrict__ out) {
    const int lane = threadIdx.x & 63;
    const int wid  = threadIdx.x >> 6;
    const int wavesTotal = gridDim.x * 4;
    const float w2v = w2[lane];
    const float b2v = b2[0];
    for (int e = blockIdx.x * 4 + wid; e < HALF_E; e += wavesTotal) {
        int s = rowIdx[e];
        int d = colIdx[e];
        float t = hA[s * 64 + lane] + hB[d * 64 + lane];
        t = fmaxf(t, 0.0f);
        float p = t * w2v;
#pragma unroll
        for (int off = 32; off; off >>= 1) p += __shfl_xor(p, off, 64);
        if (lane == 0) {
            float sv = p + b2v;
            // stable softplus = max(x,0) + log1p(exp(-|x|))
            float sp = fmaxf(sv, 0.0f) + log1pf(expf(-fabsf(sv)));
            float wv = sp + 1e-6f;
            out[e] = wv;
            out[e + HALF_E] = wv;
        }
    }
}

extern "C" void kernel_launch(void* const* d_in, const int* in_sizes, int n_in,
                              void* d_out, int out_size, void* d_ws, size_t ws_size,
                              hipStream_t stream) {
    const float* x      = (const float*)d_in[0];
    const int*   rowIdx = (const int*)d_in[1];
    const int*   colIdx = rowIdx + E_EDGES;
    const float* w_in   = (const float*)d_in[2];
    const float* b_in   = (const float*)d_in[3];
    const float* l0_m1w = (const float*)d_in[4];
    const float* l0_m1b = (const float*)d_in[5];
    const float* l0_m2w = (const float*)d_in[6];
    const float* l0_m2b = (const float*)d_in[7];
    const float* l0_u1w = (const float*)d_in[8];
    const float* l0_u1b = (const float*)d_in[9];
    const float* l0_u2w = (const float*)d_in[10];
    const float* l0_u2b = (const float*)d_in[11];
    const float* l1_m1w = (const float*)d_in[12];
    const float* l1_m1b = (const float*)d_in[13];
    const float* l1_m2w = (const float*)d_in[14];
    const float* l1_m2b = (const float*)d_in[15];
    const float* l1_u1w = (const float*)d_in[16];
    const float* l1_u1b = (const float*)d_in[17];
    const float* l1_u2w = (const float*)d_in[18];
    const float* l1_u2b = (const float*)d_in[19];
    const float* h1w    = (const float*)d_in[20];
    const float* h1b    = (const float*)d_in[21];
    const float* h2w    = (const float*)d_in[22];
    const float* h2b    = (const float*)d_in[23];

    float* out = (float*)d_out;

    float* h   = (float*)d_ws;                    // N x 64
    float* msg = h   + (size_t)N_NODES * 64;      // N x 64  (later hA)
    float* agg = msg + (size_t)N_NODES * 64;      // N x 64  (later hB)
    float* deg = agg + (size_t)N_NODES * 64;      // N

    hipMemsetAsync(deg, 0, (size_t)N_NODES * sizeof(float), stream);
    hipMemsetAsync(agg, 0, (size_t)N_NODES * 64 * sizeof(float), stream);

    k_deg<<<2048, 256, 0, stream>>>(rowIdx, deg);
    k_lin_in<<<1024, 256, 0, stream>>>(x, w_in, b_in, h);

    // ---- layer 0 ----
    k_msg<<<1024, 256, 0, stream>>>(h, l0_m1w, l0_m1b, l0_m2w, l0_m2b, msg);
    k_scatter<<<8192, 256, 0, stream>>>(rowIdx, colIdx, msg, agg);
    k_update<<<1024, 256, 0, stream>>>(h, agg, deg, l0_u1w, l0_u1b, l0_u2w, l0_u2b);

    hipMemsetAsync(agg, 0, (size_t)N_NODES * 64 * sizeof(float), stream);

    // ---- layer 1 ----
    k_msg<<<1024, 256, 0, stream>>>(h, l1_m1w, l1_m1b, l1_m2w, l1_m2b, msg);
    k_scatter<<<8192, 256, 0, stream>>>(rowIdx, colIdx, msg, agg);
    k_update<<<1024, 256, 0, stream>>>(h, agg, deg, l1_u1w, l1_u1b, l1_u2w, l1_u2b);

    // ---- head ----
    k_headpre<<<1024, 256, 0, stream>>>(h, deg, h1w, h1b, msg /*hA*/, agg /*hB*/);
    k_head<<<4096, 256, 0, stream>>>(rowIdx, colIdx, msg, agg, h2w, h2b, out);
}